// Round 2
// baseline (39.633 us; speedup 1.0000x reference)
//
#include <hip/hip_runtime.h>

typedef float  f32x4 __attribute__((ext_vector_type(4)));
typedef _Float16 h16x8 __attribute__((ext_vector_type(8)));
typedef _Float16 h16x2 __attribute__((ext_vector_type(2)));

#define LOG2E 1.4426950408889634f
#define ALPHA 0.2f

__device__ __forceinline__ float fexp2(float v) {
#if __has_builtin(__builtin_amdgcn_exp2f)
  return __builtin_amdgcn_exp2f(v);
#else
  return exp2f(v);
#endif
}

// ---------------- kernel 1: f1/f2 rows, pre-scaled by log2(e) ----------------
// f1[b*1024+t] = (emb[b,t,:] . (W@a1)) * LOG2E ; f2 likewise with a2.
__global__ __launch_bounds__(256) void fkern(
    const float* __restrict__ emb, const float* __restrict__ W,
    const float* __restrict__ a, float* __restrict__ f1, float* __restrict__ f2)
{
  __shared__ float w1s[64], w2s[64];
  const int t = threadIdx.x;
  if (t < 128) {
    const int d = t & 63;
    const float* wrow = W + d * 64;
    const float* av = a + (t >> 6) * 64;
    float s = 0.f;
#pragma unroll
    for (int h = 0; h < 64; ++h) s = fmaf(wrow[h], av[h], s);
    if (t < 64) w1s[d] = s; else w2s[d] = s;
  }
  __syncthreads();
  const int R = blockIdx.x * 64 + (t >> 2);   // global row (b*1024+t)
  const int q = t & 3;                        // quarter of the 64-dot
  const f32x4* er = (const f32x4*)(emb + (size_t)R * 64 + q * 16);
  float s1 = 0.f, s2 = 0.f;
#pragma unroll
  for (int r = 0; r < 4; ++r) {
    f32x4 v = er[r];
#pragma unroll
    for (int c = 0; c < 4; ++c) {
      s1 = fmaf(v[c], w1s[q * 16 + r * 4 + c], s1);
      s2 = fmaf(v[c], w2s[q * 16 + r * 4 + c], s2);
    }
  }
  s1 += __shfl_xor(s1, 1); s1 += __shfl_xor(s1, 2);
  s2 += __shfl_xor(s2, 1); s2 += __shfl_xor(s2, 2);
  if (q == 0) { f1[R] = s1 * LOG2E; f2[R] = s2 * LOG2E; }
}

// ---------------- kernel 2: fused softmax(P) @ [x_b | x_{b+32}] ----------------
// grid 256: b = bid>>3 (32 batches), row-tile = (bid&7)*128.  4 waves,
// each wave owns 32 rows x 128 cols.  P stays in registers as MFMA A-frags.
__global__ __launch_bounds__(256, 1) void attn_main(
    const float* __restrict__ x, const float* __restrict__ f1g,
    const float* __restrict__ f2g, float* __restrict__ out)
{
  __shared__ __attribute__((aligned(16))) _Float16 Xt[2][128 * 136]; // [d][k] pad 136
  __shared__ float f2s[1024];
  __shared__ float Zs[128];
  __shared__ float red[4];

  const int t    = threadIdx.x;
  const int wid  = t >> 6;
  const int lane = t & 63;
  const int l15  = lane & 15;
  const int g    = lane >> 4;          // k-group of this lane (0..3)
  const int b    = blockIdx.x >> 3;
  const int brow = (blockIdx.x & 7) * 128;

  // ---- prologue: f2 row -> LDS, per-batch max (all in log2-scaled domain) ----
  {
    f32x4 v = *(const f32x4*)(f2g + b * 1024 + t * 4);
    *(f32x4*)(f2s + t * 4) = v;
    float m = fmaxf(fmaxf(v[0], v[1]), fmaxf(v[2], v[3]));
#pragma unroll
    for (int off = 1; off < 64; off <<= 1) m = fmaxf(m, __shfl_xor(m, off));
    if (lane == 0) red[wid] = m;
  }

  const float f1v0 = f1g[b * 1024 + brow + wid * 32 + l15];
  const float f1v1 = f1g[b * 1024 + brow + wid * 32 + 16 + l15];

  float rv[64];  // staged global values for next chunk (fully static-indexed)

  // stage-loads for chunk kc (each wave: 8 passes of 8 dwords)
  auto stage_loads = [&](int kc) {
#pragma unroll
    for (int p = 0; p < 8; ++p) {
      const int pp = wid * 8 + p;
      const int h  = pp >> 4;
      const int j0 = (pp & 15) * 8;
      const float* base = x + (size_t)(b + 32 * h) * 65536
                            + (size_t)(kc * 128 + j0 + 2 * g) * 64 + l15;
#pragma unroll
      for (int i = 0; i < 4; ++i) {
        rv[p * 8 + i]     = base[i * 16];        // j_a, d = l15+16i
        rv[p * 8 + 4 + i] = base[64 + i * 16];   // j_b = j_a+1
      }
    }
  };
  auto stage_writes = [&](int buf) {
#pragma unroll
    for (int p = 0; p < 8; ++p) {
      const int pp = wid * 8 + p;
      const int h  = pp >> 4;
      const int k  = (pp & 15) * 8 + 2 * g;      // chunk-local j (even)
#pragma unroll
      for (int i = 0; i < 4; ++i) {
        const int row = h * 64 + l15 + 16 * i;   // d
        h16x2 hp;
        hp[0] = (_Float16)rv[p * 8 + i];         // RTN conversion for x
        hp[1] = (_Float16)rv[p * 8 + 4 + i];
        *(unsigned*)&Xt[buf][row * 136 + k] = __builtin_bit_cast(unsigned, hp);
      }
    }
  };

  stage_loads(0);
  __syncthreads();   // f2s, red ready
  const float mf2 = fmaxf(fmaxf(red[0], red[1]), fmaxf(red[2], red[3]));
  float A0, B0, A1, B1;
  { const float u = f1v0 + mf2; const float mL = fmaxf(u, ALPHA * u);
    A0 = f1v0 - mL; B0 = fmaf(ALPHA, f1v0, -mL); }
  { const float u = f1v1 + mf2; const float mL = fmaxf(u, ALPHA * u);
    A1 = f1v1 - mL; B1 = fmaf(ALPHA, f1v1, -mL); }
  stage_writes(0);
  __syncthreads();   // Xt[0] ready

  f32x4 acc[2][8] = {};
  float z0 = 0.f, z1 = 0.f;

  for (int kc = 0; kc < 8; ++kc) {
    const int buf = kc & 1;
    if (kc < 7) stage_loads(kc + 1);   // T14: issue early, write after compute
#pragma unroll
    for (int ks = 0; ks < 4; ++ks) {
      const int jb = kc * 128 + ks * 32 + g * 8;
      f32x4 f2a = *(const f32x4*)(f2s + jb);
      f32x4 f2b = *(const f32x4*)(f2s + jb + 4);
      float fv[8];
#pragma unroll
      for (int i = 0; i < 4; ++i) { fv[i] = f2a[i]; fv[4 + i] = f2b[i]; }
      h16x8 a0, a1;
#pragma unroll
      for (int jj = 0; jj < 4; ++jj) {
        const float fA = fv[2 * jj], fB = fv[2 * jj + 1];
        float p00 = fexp2(fmaxf(A0 + fA, fmaf(ALPHA, fA, B0)));
        float p01 = fexp2(fmaxf(A0 + fB, fmaf(ALPHA, fB, B0)));
        h16x2 pk0 = __builtin_bit_cast(h16x2, __builtin_amdgcn_cvt_pkrtz(p00, p01));
        a0[2 * jj] = pk0[0]; a0[2 * jj + 1] = pk0[1];
        z0 += (float)pk0[0] + (float)pk0[1];     // Z from ROUNDED p (consistency)
        float p10 = fexp2(fmaxf(A1 + fA, fmaf(ALPHA, fA, B1)));
        float p11 = fexp2(fmaxf(A1 + fB, fmaf(ALPHA, fB, B1)));
        h16x2 pk1 = __builtin_bit_cast(h16x2, __builtin_amdgcn_cvt_pkrtz(p10, p11));
        a1[2 * jj] = pk1[0]; a1[2 * jj + 1] = pk1[1];
        z1 += (float)pk1[0] + (float)pk1[1];
      }
#pragma unroll
      for (int nf = 0; nf < 8; ++nf) {
        h16x8 bf = *(const h16x8*)&Xt[buf][(nf * 16 + l15) * 136 + ks * 32 + g * 8];
        acc[0][nf] = __builtin_amdgcn_mfma_f32_16x16x32_f16(a0, bf, acc[0][nf], 0, 0, 0);
        acc[1][nf] = __builtin_amdgcn_mfma_f32_16x16x32_f16(a1, bf, acc[1][nf], 0, 0, 0);
      }
    }
    if (kc < 7) stage_writes(buf ^ 1);
    __syncthreads();
  }

  // ---- epilogue: Z reduce across k-groups, divide, store ----
  z0 += __shfl_xor(z0, 16); z0 += __shfl_xor(z0, 32);
  z1 += __shfl_xor(z1, 16); z1 += __shfl_xor(z1, 32);
  if (lane < 16) { Zs[wid * 32 + lane] = z0; Zs[wid * 32 + 16 + lane] = z1; }
  __syncthreads();
  float rz0[4], rz1[4];
#pragma unroll
  for (int r = 0; r < 4; ++r) {
    rz0[r] = 1.0f / Zs[wid * 32 + g * 4 + r];
    rz1[r] = 1.0f / Zs[wid * 32 + 16 + g * 4 + r];
  }
  const int i0 = brow + wid * 32;
#pragma unroll
  for (int nf = 0; nf < 8; ++nf) {
    const int n  = nf * 16 + l15;
    const int bo = b + ((n >= 64) ? 32 : 0);
    float* op = out + (size_t)bo * 65536 + (n & 63);
#pragma unroll
    for (int r = 0; r < 4; ++r) {
      op[(size_t)(i0 + g * 4 + r) * 64]      = acc[0][nf][r] * rz0[r];
      op[(size_t)(i0 + 16 + g * 4 + r) * 64] = acc[1][nf][r] * rz1[r];
    }
  }
}

extern "C" void kernel_launch(void* const* d_in, const int* in_sizes, int n_in,
                              void* d_out, int out_size, void* d_ws, size_t ws_size,
                              hipStream_t stream) {
  const float* emb = (const float*)d_in[0];
  const float* x   = (const float*)d_in[1];
  const float* W   = (const float*)d_in[2];
  const float* a   = (const float*)d_in[3];
  float* f1 = (float*)d_ws;          // 32*1024 floats
  float* f2 = f1 + 32 * 1024;        // 32*1024 floats
  fkern<<<512, 256, 0, stream>>>(emb, W, a, f1, f2);
  attn_main<<<256, 256, 0, stream>>>(x, f1, f2, (float*)d_out);
}

// Round 3
// 37.757 us; speedup vs baseline: 1.0497x; 1.0497x over previous
//
#include <hip/hip_runtime.h>

typedef float  f32x4 __attribute__((ext_vector_type(4)));
typedef _Float16 h16x8 __attribute__((ext_vector_type(8)));
typedef _Float16 h16x2 __attribute__((ext_vector_type(2)));

#define LOG2E 1.4426950408889634f
#define ALPHA 0.2f

__device__ __forceinline__ float fexp2(float v) {
#if __has_builtin(__builtin_amdgcn_exp2f)
  return __builtin_amdgcn_exp2f(v);
#else
  return exp2f(v);
#endif
}

// ---------------- kernel 1: f1/f2 rows, pre-scaled by log2(e) ----------------
__global__ __launch_bounds__(256) void fkern(
    const float* __restrict__ emb, const float* __restrict__ W,
    const float* __restrict__ a, float* __restrict__ f1, float* __restrict__ f2)
{
  __shared__ float w1s[64], w2s[64];
  const int t = threadIdx.x;
  if (t < 128) {
    const int d = t & 63;
    const float* wrow = W + d * 64;
    const float* av = a + (t >> 6) * 64;
    float s = 0.f;
#pragma unroll
    for (int h = 0; h < 64; ++h) s = fmaf(wrow[h], av[h], s);
    if (t < 64) w1s[d] = s; else w2s[d] = s;
  }
  __syncthreads();
  const int R = blockIdx.x * 64 + (t >> 2);
  const int q = t & 3;
  const f32x4* er = (const f32x4*)(emb + (size_t)R * 64 + q * 16);
  float s1 = 0.f, s2 = 0.f;
#pragma unroll
  for (int r = 0; r < 4; ++r) {
    f32x4 v = er[r];
#pragma unroll
    for (int c = 0; c < 4; ++c) {
      s1 = fmaf(v[c], w1s[q * 16 + r * 4 + c], s1);
      s2 = fmaf(v[c], w2s[q * 16 + r * 4 + c], s2);
    }
  }
  s1 += __shfl_xor(s1, 1); s1 += __shfl_xor(s1, 2);
  s2 += __shfl_xor(s2, 1); s2 += __shfl_xor(s2, 2);
  if (q == 0) { f1[R] = s1 * LOG2E; f2[R] = s2 * LOG2E; }
}

// ---------------- kernel 2: fused softmax(P) @ [x_b | x_{b+32}] ----------------
// grid 256, 512 threads (8 waves).  b = bid>>3, row-tile = (bid&7)*128.
// Wave = (wr 0..3, wc 0..1): rows brow+wr*32+{0..31}, cols wc*64 + nf*16.
// P stays in registers as MFMA A-frags; Z via ones-column MFMA.
__global__ __launch_bounds__(512, 1) void attn_main(
    const float* __restrict__ x, const float* __restrict__ f1g,
    const float* __restrict__ f2g, float* __restrict__ out)
{
  __shared__ __attribute__((aligned(16))) _Float16 Xt[2][128 * 136]; // [d][k] pad 136
  __shared__ float f2s[1024];
  __shared__ float red[4];

  const int t    = threadIdx.x;
  const int wid  = t >> 6;
  const int lane = t & 63;
  const int l15  = lane & 15;
  const int g    = lane >> 4;          // k-group (0..3)
  const int wc   = wid & 1;            // col half
  const int wr   = wid >> 1;           // row block (0..3)
  const int b    = blockIdx.x >> 3;
  const int brow = (blockIdx.x & 7) * 128;

  // ---- prologue: f2 row -> LDS, per-batch max (log2-scaled domain) ----
  if (t < 256) {
    f32x4 v = *(const f32x4*)(f2g + b * 1024 + t * 4);
    *(f32x4*)(f2s + t * 4) = v;
    float m = fmaxf(fmaxf(v[0], v[1]), fmaxf(v[2], v[3]));
#pragma unroll
    for (int off = 1; off < 64; off <<= 1) m = fmaxf(m, __shfl_xor(m, off));
    if (lane == 0) red[wid] = m;
  }

  const float f1v0 = f1g[b * 1024 + brow + wr * 32 + l15];
  const float f1v1 = f1g[b * 1024 + brow + wr * 32 + 16 + l15];

  float rv[32];  // staged global values for next chunk (static-indexed)

  auto stage_loads = [&](int kc) {
#pragma unroll
    for (int p = 0; p < 4; ++p) {
      const int pp = wid * 4 + p;
      const int h  = pp >> 4;
      const int j0 = (pp & 15) * 8;
      const float* base = x + (size_t)(b + 32 * h) * 65536
                            + (size_t)(kc * 128 + j0 + 2 * g) * 64 + l15;
#pragma unroll
      for (int i = 0; i < 4; ++i) {
        rv[p * 8 + i]     = base[i * 16];        // j_a, d = l15+16i
        rv[p * 8 + 4 + i] = base[64 + i * 16];   // j_b = j_a+1
      }
    }
  };
  auto stage_writes = [&](int buf) {
#pragma unroll
    for (int p = 0; p < 4; ++p) {
      const int pp = wid * 4 + p;
      const int h  = pp >> 4;
      const int k  = (pp & 15) * 8 + 2 * g;      // chunk-local j (even)
#pragma unroll
      for (int i = 0; i < 4; ++i) {
        const int row = h * 64 + l15 + 16 * i;   // d
        h16x2 hp;
        hp[0] = (_Float16)rv[p * 8 + i];
        hp[1] = (_Float16)rv[p * 8 + 4 + i];
        *(unsigned*)&Xt[buf][row * 136 + k] = __builtin_bit_cast(unsigned, hp);
      }
    }
  };

  stage_loads(0);
  __syncthreads();   // f2s, red ready
  const float mf2 = fmaxf(fmaxf(red[0], red[1]), fmaxf(red[2], red[3]));
  float A0, B0, A1, B1;
  { const float u = f1v0 + mf2; const float mL = fmaxf(u, ALPHA * u);
    A0 = f1v0 - mL; B0 = fmaf(ALPHA, f1v0, -mL); }
  { const float u = f1v1 + mf2; const float mL = fmaxf(u, ALPHA * u);
    A1 = f1v1 - mL; B1 = fmaf(ALPHA, f1v1, -mL); }
  stage_writes(0);
  __syncthreads();   // Xt[0] ready

  f32x4 acc[2][4] = {};
  f32x4 accz[2] = {};
  h16x8 ones;
#pragma unroll
  for (int i = 0; i < 8; ++i) ones[i] = (_Float16)1.0f;

  for (int kc = 0; kc < 8; ++kc) {
    const int buf = kc & 1;
    if (kc < 7) stage_loads(kc + 1);   // T14: issue early, write after compute
#pragma unroll
    for (int ks = 0; ks < 4; ++ks) {
      const int jb = kc * 128 + ks * 32 + g * 8;
      f32x4 f2a = *(const f32x4*)(f2s + jb);
      f32x4 f2b = *(const f32x4*)(f2s + jb + 4);
      float fv[8];
#pragma unroll
      for (int i = 0; i < 4; ++i) { fv[i] = f2a[i]; fv[4 + i] = f2b[i]; }
      h16x8 a0, a1;
#pragma unroll
      for (int jj = 0; jj < 4; ++jj) {
        const float fA = fv[2 * jj], fB = fv[2 * jj + 1];
        float p00 = fexp2(fmaxf(A0 + fA, fmaf(ALPHA, fA, B0)));
        float p01 = fexp2(fmaxf(A0 + fB, fmaf(ALPHA, fB, B0)));
        h16x2 pk0 = __builtin_bit_cast(h16x2, __builtin_amdgcn_cvt_pkrtz(p00, p01));
        a0[2 * jj] = pk0[0]; a0[2 * jj + 1] = pk0[1];
        float p10 = fexp2(fmaxf(A1 + fA, fmaf(ALPHA, fA, B1)));
        float p11 = fexp2(fmaxf(A1 + fB, fmaf(ALPHA, fB, B1)));
        h16x2 pk1 = __builtin_bit_cast(h16x2, __builtin_amdgcn_cvt_pkrtz(p10, p11));
        a1[2 * jj] = pk1[0]; a1[2 * jj + 1] = pk1[1];
      }
#pragma unroll
      for (int nf = 0; nf < 4; ++nf) {
        h16x8 bf = *(const h16x8*)&Xt[buf][(wc * 64 + nf * 16 + l15) * 136 + ks * 32 + g * 8];
        acc[0][nf] = __builtin_amdgcn_mfma_f32_16x16x32_f16(a0, bf, acc[0][nf], 0, 0, 0);
        acc[1][nf] = __builtin_amdgcn_mfma_f32_16x16x32_f16(a1, bf, acc[1][nf], 0, 0, 0);
      }
      accz[0] = __builtin_amdgcn_mfma_f32_16x16x32_f16(a0, ones, accz[0], 0, 0, 0);
      accz[1] = __builtin_amdgcn_mfma_f32_16x16x32_f16(a1, ones, accz[1], 0, 0, 0);
    }
    if (kc < 7) stage_writes(buf ^ 1);
    __syncthreads();
  }

  // ---- epilogue: Z is in accz per-row in-lane; divide and store ----
  float rz0[4], rz1[4];
#pragma unroll
  for (int r = 0; r < 4; ++r) {
    rz0[r] = 1.0f / accz[0][r];
    rz1[r] = 1.0f / accz[1][r];
  }
  const int i0 = brow + wr * 32;
#pragma unroll
  for (int nf = 0; nf < 4; ++nf) {
    const int n  = wc * 64 + nf * 16 + l15;
    const int bo = b + ((n >= 64) ? 32 : 0);
    float* op = out + (size_t)bo * 65536 + (n & 63);
#pragma unroll
    for (int r = 0; r < 4; ++r) {
      op[(size_t)(i0 + g * 4 + r) * 64]      = acc[0][nf][r] * rz0[r];
      op[(size_t)(i0 + 16 + g * 4 + r) * 64] = acc[1][nf][r] * rz1[r];
    }
  }
}

extern "C" void kernel_launch(void* const* d_in, const int* in_sizes, int n_in,
                              void* d_out, int out_size, void* d_ws, size_t ws_size,
                              hipStream_t stream) {
  const float* emb = (const float*)d_in[0];
  const float* x   = (const float*)d_in[1];
  const float* W   = (const float*)d_in[2];
  const float* a   = (const float*)d_in[3];
  float* f1 = (float*)d_ws;          // 32*1024 floats
  float* f2 = f1 + 32 * 1024;        // 32*1024 floats
  fkern<<<512, 256, 0, stream>>>(emb, W, a, f1, f2);
  attn_main<<<256, 512, 0, stream>>>(x, f1, f2, (float*)d_out);
}